// Round 4
// baseline (470.215 us; speedup 1.0000x reference)
//
#include <hip/hip_runtime.h>

typedef unsigned short u16;
typedef unsigned int   u32;

// ============================================================
// K1: conv(8ch, 3x3, stride 10, pad 1) + clip(-1,1) + sigmoid(10x)
//     + where(>0.5, keep, 0).  One thread per output element.
//     vals: (1024, 800) f32, index = b*800 + o*100 + oh*10 + ow
// ============================================================
__global__ __launch_bounds__(256) void k1_conv(
    const float* __restrict__ images,   // (1024,3,96,96)
    const float* __restrict__ conv_w,   // (8,3,3,3) OIHW
    float* __restrict__ vals)           // (1024,800)
{
    int tid = blockIdx.x * 256 + threadIdx.x;   // < 819200
    int b  = tid / 800;
    int r  = tid - b * 800;
    int o  = r / 100;
    int p  = r - o * 100;
    int oh = p / 10;
    int ow = p - oh * 10;

    float sum = 0.0f;
    for (int ic = 0; ic < 3; ic++) {
        for (int kh = 0; kh < 3; kh++) {
            int ih = oh * 10 + kh - 1;
            if (ih < 0 || ih >= 96) continue;
            for (int kw = 0; kw < 3; kw++) {
                int iw = ow * 10 + kw - 1;
                if (iw < 0 || iw >= 96) continue;
                float img = images[((b * 3 + ic) * 96 + ih) * 96 + iw];
                float wv  = conv_w[((o * 3 + ic) * 3 + kh) * 3 + kw];
                sum += img * wv;
            }
        }
    }
    float xc = fminf(fmaxf(sum, -1.0f), 1.0f);
    float binary = 1.0f / (1.0f + expf(-10.0f * xc));
    vals[tid] = (binary > 0.5f) ? binary : 0.0f;
}

// ============================================================
// K2: l0 = clip(vals @ ft_w + ft_b, 0, 1)
//     Naive: one thread per output element.
// ============================================================
__global__ __launch_bounds__(256) void k2_feat(
    const float* __restrict__ vals,   // (1024,800)
    const float* __restrict__ ft_w,   // (800,1024)
    const float* __restrict__ ft_b,   // (1024,)
    float* __restrict__ l0)           // (1024,1024)
{
    int m = blockIdx.x;
    int n = blockIdx.y * 256 + threadIdx.x;
    const float* a = vals + m * 800;

    float acc = ft_b[n];
    for (int k = 0; k < 800; k++)
        acc += a[k] * ft_w[k * 1024 + n];

    l0[m * 1024 + n] = fminf(fmaxf(acc, 0.0f), 1.0f);
}

// ============================================================
// K3: tail MLP, one THREAD per batch row (naive, no shuffles).
//     l0c[k]     = l0[k] * l0[k+512] * (127/128)      k < 512
//     l0c[512+k] = l0[k] * (127/128)
//     h1(15) -> h2(32) -> out(1)
// ============================================================
__global__ __launch_bounds__(256) void k3_tail(
    const float* __restrict__ l0,  // (1024,1024)
    const float* __restrict__ w1,  // (15,1024)
    const float* __restrict__ b1,  // (15,)
    const float* __restrict__ w2,  // (32,15)
    const float* __restrict__ b2,  // (32,)
    const float* __restrict__ w3,  // (1,32)
    const float* __restrict__ b3,  // (1,)
    float* __restrict__ out)       // (1024,) f32  <-- the one change
{
    int b = blockIdx.x * 256 + threadIdx.x;   // grid 4 x 256 = 1024
    const float* row = l0 + b * 1024;
    const float cc = 127.0f / 128.0f;

    float h1[15];
    #pragma unroll
    for (int j = 0; j < 15; j++) h1[j] = b1[j];

    for (int k = 0; k < 512; k++) {
        float x0 = row[k];
        float x1 = row[k + 512];
        float pa = x0 * x1 * cc;    // l0c[k]
        float pb = x0 * cc;         // l0c[512+k]
        #pragma unroll
        for (int j = 0; j < 15; j++)
            h1[j] += pa * w1[j * 1024 + k] + pb * w1[j * 1024 + 512 + k];
    }
    #pragma unroll
    for (int j = 0; j < 15; j++) h1[j] = fmaxf(h1[j], 0.0f);

    float o = b3[0];
    for (int n = 0; n < 32; n++) {
        float h2 = b2[n];
        #pragma unroll
        for (int j = 0; j < 15; j++) h2 += h1[j] * w2[n * 15 + j];
        h2 = fmaxf(h2, 0.0f);
        o += h2 * w3[n];
    }
    out[b] = o;
}

// ============================================================
extern "C" void kernel_launch(void* const* d_in, const int* in_sizes, int n_in,
                              void* d_out, int out_size, void* d_ws, size_t ws_size,
                              hipStream_t stream) {
    const float* images = (const float*)d_in[0];
    const float* conv_w = (const float*)d_in[1];
    const float* ft_w   = (const float*)d_in[2];
    const float* ft_b   = (const float*)d_in[3];
    const float* w1     = (const float*)d_in[4];
    const float* b1     = (const float*)d_in[5];
    const float* w2     = (const float*)d_in[6];
    const float* b2     = (const float*)d_in[7];
    const float* w3     = (const float*)d_in[8];
    const float* b3     = (const float*)d_in[9];
    float* out = (float*)d_out;

    float* vals = (float*)d_ws;            // 1024*800 f32
    float* l0   = vals + 1024 * 800;       // 1024*1024 f32

    k1_conv<<<3200, 256, 0, stream>>>(images, conv_w, vals);
    k2_feat<<<dim3(1024, 4), 256, 0, stream>>>(vals, ft_w, ft_b, l0);
    k3_tail<<<4, 256, 0, stream>>>(l0, w1, b1, w2, b2, w3, b3, out);
}

// Round 5
// 247.764 us; speedup vs baseline: 1.8978x; 1.8978x over previous
//
#include <hip/hip_runtime.h>

typedef unsigned short u16;
typedef unsigned int   u32;

// ============================================================
// K1: conv(8ch,3x3,stride10,pad1) + clip + sigmoid(10x) + mask(>0.5)
// One block per image. Stage the 29 needed rows x 3ch into LDS
// (coalesced), then 800 outputs from LDS.
// Needed rows: {0,1} U {10g-1,10g,10g+1 : g=1..9}; LDS row index
// lr = 3*oh + kh - 1   (ih = 10*((lr+1)/3) + (lr+1)%3 - 1)
// ============================================================
__global__ __launch_bounds__(256) void k1_conv(
    const float* __restrict__ images,   // (1024,3,96,96)
    const float* __restrict__ conv_w,   // (8,3,3,3) OIHW
    float* __restrict__ vals)           // (1024,800)
{
    __shared__ float img_s[3][29][96];   // 33408 B
    __shared__ float w[216];

    int b = blockIdx.x;
    int t = threadIdx.x;
    if (t < 216) w[t] = conv_w[t];

    for (int i = t; i < 3 * 29 * 96; i += 256) {
        int ch  = i / (29 * 96);
        int rem = i - ch * (29 * 96);
        int lr  = rem / 96;
        int x   = rem - lr * 96;
        int ih  = 10 * ((lr + 1) / 3) + (lr + 1) % 3 - 1;
        img_s[ch][lr][x] = images[((b * 3 + ch) * 96 + ih) * 96 + x];
    }
    __syncthreads();

    for (int r = t; r < 800; r += 256) {
        int o  = r / 100;
        int p  = r - o * 100;
        int oh = p / 10;
        int ow = p - oh * 10;

        float sum = 0.0f;
        #pragma unroll
        for (int ic = 0; ic < 3; ic++) {
            const float* wc = &w[o * 27 + ic * 9];
            #pragma unroll
            for (int kh = 0; kh < 3; kh++) {
                int lr = 3 * oh + kh - 1;
                if (lr < 0) continue;            // oh=0,kh=0 (row -1)
                #pragma unroll
                for (int kw = 0; kw < 3; kw++) {
                    int iw = ow * 10 + kw - 1;
                    if (iw < 0) continue;        // iw <= 91 always
                    sum = fmaf(img_s[ic][lr][iw], wc[kh * 3 + kw], sum);
                }
            }
        }
        float xc = fminf(fmaxf(sum, -1.0f), 1.0f);
        float binary = 1.0f / (1.0f + __expf(-10.0f * xc));
        vals[b * 800 + r] = (binary > 0.5f) ? binary : 0.0f;
    }
}

// ============================================================
// K2: l0 = clip(vals @ ft_w + ft_b, 0, 1)
// fp32 tiled GEMM: BM=BN=64, BK=16, 4x4 microtile, 256 threads
// (structure validated: bit-identical output vs naive in R2/R3)
// ============================================================
__global__ __launch_bounds__(256) void k2_feat(
    const float* __restrict__ A,    // (1024,800)
    const float* __restrict__ Bw,   // (800,1024)
    const float* __restrict__ bias, // (1024,)
    float* __restrict__ C)          // (1024,1024)
{
    __shared__ float As[16][64];   // transposed: As[k][m]
    __shared__ float Bs[16][64];

    int t  = threadIdx.x;
    int tx = t & 15, ty = t >> 4;
    int m0 = blockIdx.y * 64, n0 = blockIdx.x * 64;

    float acc[4][4] = {};

    int ar = t >> 2;            // 0..63
    int ac = (t & 3) << 2;      // 0,4,8,12
    int br = t >> 4;            // 0..15
    int bc = (t & 15) << 2;     // 0..60

    for (int k0 = 0; k0 < 800; k0 += 16) {
        float4 a = *(const float4*)(A + (m0 + ar) * 800 + k0 + ac);
        As[ac + 0][ar] = a.x; As[ac + 1][ar] = a.y;
        As[ac + 2][ar] = a.z; As[ac + 3][ar] = a.w;

        float4 bv4 = *(const float4*)(Bw + (k0 + br) * 1024 + n0 + bc);
        Bs[br][bc + 0] = bv4.x; Bs[br][bc + 1] = bv4.y;
        Bs[br][bc + 2] = bv4.z; Bs[br][bc + 3] = bv4.w;
        __syncthreads();

        #pragma unroll
        for (int kk = 0; kk < 16; kk++) {
            float4 av = *(const float4*)&As[kk][ty << 2];
            float4 bv = *(const float4*)&Bs[kk][tx << 2];
            float am[4] = {av.x, av.y, av.z, av.w};
            float bm[4] = {bv.x, bv.y, bv.z, bv.w};
            #pragma unroll
            for (int i = 0; i < 4; i++)
                #pragma unroll
                for (int j = 0; j < 4; j++)
                    acc[i][j] = fmaf(am[i], bm[j], acc[i][j]);
        }
        __syncthreads();
    }

    int n = n0 + (tx << 2);
    float b0 = bias[n + 0], b1_ = bias[n + 1];
    float b2_ = bias[n + 2], b3_ = bias[n + 3];
    #pragma unroll
    for (int i = 0; i < 4; i++) {
        int m = m0 + (ty << 2) + i;
        float4 o;
        o.x = fminf(fmaxf(acc[i][0] + b0, 0.f), 1.f);
        o.y = fminf(fmaxf(acc[i][1] + b1_, 0.f), 1.f);
        o.z = fminf(fmaxf(acc[i][2] + b2_, 0.f), 1.f);
        o.w = fminf(fmaxf(acc[i][3] + b3_, 0.f), 1.f);
        *(float4*)(C + m * 1024 + n) = o;
    }
}

// ============================================================
// K3: per-row tail, one wave per batch row (validated in R2/R3).
// ============================================================
__global__ __launch_bounds__(64) void k3_tail(
    const float* __restrict__ l0,  // (1024,1024)
    const float* __restrict__ w1,  // (15,1024)
    const float* __restrict__ b1,  // (15,)
    const float* __restrict__ w2,  // (32,15)
    const float* __restrict__ b2,  // (32,)
    const float* __restrict__ w3,  // (1,32)
    const float* __restrict__ b3,  // (1,)
    float* __restrict__ out)       // (1024,) f32
{
    int b = blockIdx.x;
    int t = threadIdx.x;
    const float* row = l0 + b * 1024;
    const float cc = 0.9921875f;   // 127/128 exact

    float acc[15];
    #pragma unroll
    for (int j = 0; j < 15; j++) acc[j] = 0.f;

    for (int k = t; k < 1024; k += 64) {   // wave-uniform branch
        float v;
        if (k < 512) v = row[k] * row[k + 512] * cc;
        else         v = row[k - 512] * cc;
        #pragma unroll
        for (int j = 0; j < 15; j++)
            acc[j] = fmaf(v, w1[j * 1024 + k], acc[j]);
    }

    #pragma unroll
    for (int j = 0; j < 15; j++) {
        #pragma unroll
        for (int m = 32; m >= 1; m >>= 1)
            acc[j] += __shfl_xor(acc[j], m, 64);
    }
    float h1[15];
    #pragma unroll
    for (int j = 0; j < 15; j++) h1[j] = fmaxf(acc[j] + b1[j], 0.f);

    float contrib = 0.f;
    if (t < 32) {
        float h2 = b2[t];
        #pragma unroll
        for (int j = 0; j < 15; j++) h2 = fmaf(h1[j], w2[t * 15 + j], h2);
        h2 = fmaxf(h2, 0.f);
        contrib = h2 * w3[t];
    }
    #pragma unroll
    for (int m = 32; m >= 1; m >>= 1) contrib += __shfl_xor(contrib, m, 64);

    if (t == 0) out[b] = contrib + b3[0];
}

// ============================================================
extern "C" void kernel_launch(void* const* d_in, const int* in_sizes, int n_in,
                              void* d_out, int out_size, void* d_ws, size_t ws_size,
                              hipStream_t stream) {
    const float* images = (const float*)d_in[0];
    const float* conv_w = (const float*)d_in[1];
    const float* ft_w   = (const float*)d_in[2];
    const float* ft_b   = (const float*)d_in[3];
    const float* w1     = (const float*)d_in[4];
    const float* b1     = (const float*)d_in[5];
    const float* w2     = (const float*)d_in[6];
    const float* b2     = (const float*)d_in[7];
    const float* w3     = (const float*)d_in[8];
    const float* b3     = (const float*)d_in[9];
    float* out = (float*)d_out;

    float* vals = (float*)d_ws;            // 1024*800 f32
    float* l0   = vals + 1024 * 800;       // 1024*1024 f32

    k1_conv<<<1024, 256, 0, stream>>>(images, conv_w, vals);
    k2_feat<<<dim3(16, 16), 256, 0, stream>>>(vals, ft_w, ft_b, l0);
    k3_tail<<<1024, 64, 0, stream>>>(l0, w1, b1, w2, b2, w3, b3, out);
}

// Round 6
// 214.991 us; speedup vs baseline: 2.1871x; 1.1524x over previous
//
#include <hip/hip_runtime.h>

typedef unsigned short u16;
typedef unsigned int   u32;
typedef __attribute__((ext_vector_type(8))) short short8;   // 8 bf16 (m89-verified type)
typedef __attribute__((ext_vector_type(4))) float f32x4;

__device__ __forceinline__ u16 f2bf(float f) {
    union { float f; u32 i; } v; v.f = f;
    u32 x = v.i;
    return (u16)((x + 0x7fffu + ((x >> 16) & 1u)) >> 16);   // RNE
}
__device__ __forceinline__ float bf2f(u16 u) {
    union { u32 i; float f; } v; v.i = ((u32)u) << 16; return v.f;
}

// ============================================================
// K0: transpose + hi/lo split of ft_w (800x1024 f32) ->
//     Bt_hi/Bt_lo (1024x800 bf16, n-major)
// ============================================================
__global__ __launch_bounds__(256) void k0_split(
    const float* __restrict__ ft_w,
    u16* __restrict__ bth, u16* __restrict__ btl)
{
    __shared__ float tile[32][33];
    int k0 = blockIdx.x * 32, n0 = blockIdx.y * 32;
    int tx = threadIdx.x & 31, ty = threadIdx.x >> 5;   // ty 0..7
    #pragma unroll
    for (int i = 0; i < 4; i++) {
        int k = ty + i * 8;
        tile[k][tx] = ft_w[(k0 + k) * 1024 + n0 + tx];
    }
    __syncthreads();
    #pragma unroll
    for (int i = 0; i < 4; i++) {
        int n = ty + i * 8;
        float wv = tile[tx][n];
        u16 hi = f2bf(wv);
        float lo = wv - bf2f(hi);
        bth[(n0 + n) * 800 + k0 + tx] = hi;
        btl[(n0 + n) * 800 + k0 + tx] = f2bf(lo);
    }
}

// ============================================================
// K1: conv + clip + sigmoid + mask, LDS row staging (validated R5),
//     now emitting hi/lo bf16 split of vals.
// ============================================================
__global__ __launch_bounds__(256) void k1_conv(
    const float* __restrict__ images,   // (1024,3,96,96)
    const float* __restrict__ conv_w,   // (8,3,3,3)
    u16* __restrict__ vh, u16* __restrict__ vl)   // (1024,800) each
{
    __shared__ float img_s[3][29][96];
    __shared__ float w[216];

    int b = blockIdx.x;
    int t = threadIdx.x;
    if (t < 216) w[t] = conv_w[t];

    for (int i = t; i < 3 * 29 * 96; i += 256) {
        int ch  = i / (29 * 96);
        int rem = i - ch * (29 * 96);
        int lr  = rem / 96;
        int x   = rem - lr * 96;
        int ih  = 10 * ((lr + 1) / 3) + (lr + 1) % 3 - 1;
        img_s[ch][lr][x] = images[((b * 3 + ch) * 96 + ih) * 96 + x];
    }
    __syncthreads();

    for (int ridx = t; ridx < 800; ridx += 256) {
        int o  = ridx / 100;
        int p  = ridx - o * 100;
        int oh = p / 10;
        int ow = p - oh * 10;

        float sum = 0.0f;
        #pragma unroll
        for (int ic = 0; ic < 3; ic++) {
            const float* wc = &w[o * 27 + ic * 9];
            #pragma unroll
            for (int kh = 0; kh < 3; kh++) {
                int lr = 3 * oh + kh - 1;
                if (lr < 0) continue;
                #pragma unroll
                for (int kw = 0; kw < 3; kw++) {
                    int iw = ow * 10 + kw - 1;
                    if (iw < 0) continue;
                    sum = fmaf(img_s[ic][lr][iw], wc[kh * 3 + kw], sum);
                }
            }
        }
        float xc = fminf(fmaxf(sum, -1.0f), 1.0f);
        float binary = 1.0f / (1.0f + __expf(-10.0f * xc));
        float v = (binary > 0.5f) ? binary : 0.0f;
        u16 hi = f2bf(v);
        vh[b * 800 + ridx] = hi;
        vl[b * 800 + ridx] = f2bf(v - bf2f(hi));
    }
}

// ============================================================
// K2: l0 = clip(vals @ ft_w + ft_b, 0, 1) via split-bf16 MFMA.
// C = Ah*Bh + Ah*Bl + Al*Bh  (Al*Bl dropped, <=2e-4 total).
// 64x64 tile, 4 waves, 2x2 frags of 16x16x32 per wave, BK=32.
// LDS rows padded to 40 u16 (80B): 20-dword bank stride -> 2-way only.
// ============================================================
__global__ __launch_bounds__(256) void k2_mfma(
    const u16* __restrict__ Ah, const u16* __restrict__ Al,   // (1024,800)
    const u16* __restrict__ Bh, const u16* __restrict__ Bl,   // (1024,800) n-major
    const float* __restrict__ bias,
    float* __restrict__ C)                                    // (1024,1024)
{
    __shared__ u16 sAh[64 * 40], sAl[64 * 40], sBh[64 * 40], sBl[64 * 40];
    int t = threadIdx.x;
    int m0 = blockIdx.y * 64, n0 = blockIdx.x * 64;
    int w = t >> 6, lane = t & 63;
    int quad = lane >> 4, lo4 = lane & 15;
    int wm = (w >> 1) * 32, wn = (w & 1) * 32;

    int sr = t >> 2;   // staging row 0..63
    int sq = t & 3;    // 8-elem chunk 0..3
    const u16* gAh = Ah + (m0 + sr) * 800 + sq * 8;
    const u16* gAl = Al + (m0 + sr) * 800 + sq * 8;
    const u16* gBh = Bh + (n0 + sr) * 800 + sq * 8;
    const u16* gBl = Bl + (n0 + sr) * 800 + sq * 8;
    int sdst = sr * 40 + sq * 8;

    f32x4 acc[2][2] = {};

    for (int k0 = 0; k0 < 800; k0 += 32) {
        *(uint4*)&sAh[sdst] = *(const uint4*)(gAh + k0);
        *(uint4*)&sAl[sdst] = *(const uint4*)(gAl + k0);
        *(uint4*)&sBh[sdst] = *(const uint4*)(gBh + k0);
        *(uint4*)&sBl[sdst] = *(const uint4*)(gBl + k0);
        __syncthreads();

        short8 a_h[2], a_l[2], b_h[2], b_l[2];
        #pragma unroll
        for (int f = 0; f < 2; f++) {
            int mi = (wm + f * 16 + lo4) * 40 + quad * 8;
            a_h[f] = *(const short8*)&sAh[mi];
            a_l[f] = *(const short8*)&sAl[mi];
            int ni = (wn + f * 16 + lo4) * 40 + quad * 8;
            b_h[f] = *(const short8*)&sBh[ni];
            b_l[f] = *(const short8*)&sBl[ni];
        }
        #pragma unroll
        for (int fm = 0; fm < 2; fm++)
            #pragma unroll
            for (int fn = 0; fn < 2; fn++) {
                acc[fm][fn] = __builtin_amdgcn_mfma_f32_16x16x32_bf16(a_h[fm], b_h[fn], acc[fm][fn], 0, 0, 0);
                acc[fm][fn] = __builtin_amdgcn_mfma_f32_16x16x32_bf16(a_h[fm], b_l[fn], acc[fm][fn], 0, 0, 0);
                acc[fm][fn] = __builtin_amdgcn_mfma_f32_16x16x32_bf16(a_l[fm], b_h[fn], acc[fm][fn], 0, 0, 0);
            }
        __syncthreads();
    }

    // C/D layout (m89/m91-verified): col = lane&15, row = quad*4 + reg
    #pragma unroll
    for (int fm = 0; fm < 2; fm++) {
        #pragma unroll
        for (int fn = 0; fn < 2; fn++) {
            int n = n0 + wn + fn * 16 + lo4;
            float bv = bias[n];
            #pragma unroll
            for (int r = 0; r < 4; r++) {
                int m = m0 + wm + fm * 16 + quad * 4 + r;
                float v = acc[fm][fn][r] + bv;
                C[m * 1024 + n] = fminf(fmaxf(v, 0.f), 1.f);
            }
        }
    }
}

// ============================================================
// K3: per-row tail, one wave per row, 4 waves per block.
// ============================================================
__global__ __launch_bounds__(256) void k3_tail(
    const float* __restrict__ l0,  // (1024,1024)
    const float* __restrict__ w1,  // (15,1024)
    const float* __restrict__ b1,
    const float* __restrict__ w2,  // (32,15)
    const float* __restrict__ b2,
    const float* __restrict__ w3,  // (1,32)
    const float* __restrict__ b3,
    float* __restrict__ out)       // (1024,)
{
    int wave = threadIdx.x >> 6;
    int lane = threadIdx.x & 63;
    int b = blockIdx.x * 4 + wave;
    const float* row = l0 + b * 1024;
    const float cc = 0.9921875f;   // 127/128

    float acc[15];
    #pragma unroll
    for (int j = 0; j < 15; j++) acc[j] = 0.f;

    for (int k = lane; k < 1024; k += 64) {   // wave-uniform branch
        float v;
        if (k < 512) v = row[k] * row[k + 512] * cc;
        else         v = row[k - 512] * cc;
        #pragma unroll
        for (int j = 0; j < 15; j++)
            acc[j] = fmaf(v, w1[j * 1024 + k], acc[j]);
    }

    #pragma unroll
    for (int j = 0; j < 15; j++) {
        #pragma unroll
        for (int m = 32; m >= 1; m >>= 1)
            acc[j] += __shfl_xor(acc[j], m, 64);
    }
    float h1[15];
    #pragma unroll
    for (int j = 0; j < 15; j++) h1[j] = fmaxf(acc[j] + b1[j], 0.f);

    float contrib = 0.f;
    if (lane < 32) {
        float h2 = b2[lane];
        #pragma unroll
        for (int j = 0; j < 15; j++) h2 = fmaf(h1[j], w2[lane * 15 + j], h2);
        h2 = fmaxf(h2, 0.f);
        contrib = h2 * w3[lane];
    }
    #pragma unroll
    for (int m = 32; m >= 1; m >>= 1) contrib += __shfl_xor(contrib, m, 64);

    if (lane == 0) out[b] = contrib + b3[0];
}

// ============================================================
extern "C" void kernel_launch(void* const* d_in, const int* in_sizes, int n_in,
                              void* d_out, int out_size, void* d_ws, size_t ws_size,
                              hipStream_t stream) {
    const float* images = (const float*)d_in[0];
    const float* conv_w = (const float*)d_in[1];
    const float* ft_w   = (const float*)d_in[2];
    const float* ft_b   = (const float*)d_in[3];
    const float* w1     = (const float*)d_in[4];
    const float* b1     = (const float*)d_in[5];
    const float* w2     = (const float*)d_in[6];
    const float* b2     = (const float*)d_in[7];
    const float* w3     = (const float*)d_in[8];
    const float* b3     = (const float*)d_in[9];
    float* out = (float*)d_out;

    const int NV = 1024 * 800;                 // 819200
    u16* vh  = (u16*)d_ws;                     // bf16 hi of vals
    u16* vl  = vh + NV;                        // bf16 lo
    u16* bth = vl + NV;                        // ft_w^T hi (n-major)
    u16* btl = bth + NV;                       // ft_w^T lo
    float* l0 = (float*)(btl + NV);            // (1024,1024) f32, 16B-aligned

    k0_split<<<dim3(25, 32), 256, 0, stream>>>(ft_w, bth, btl);
    k1_conv<<<1024, 256, 0, stream>>>(images, conv_w, vh, vl);
    k2_mfma<<<dim3(16, 16), 256, 0, stream>>>(vh, vl, bth, btl, ft_b, l0);
    k3_tail<<<256, 256, 0, stream>>>(l0, w1, b1, w2, b2, w3, b3, out);
}